// Round 1
// baseline (954.683 us; speedup 1.0000x reference)
//
#include <hip/hip_runtime.h>
#include <hip/hip_bf16.h>

// QuantLinear: y[t,o] = (sum_k x[t,k] * (q[o,k]-8)) * scale[o] + bias[o]
// Strategy: scale factors out of the K-reduction -> plain bf16 MFMA GEMM on
// (q-8) (exact in bf16), scale/bias applied in epilogue.
// Pass 1: convert x (fp32->bf16 RNE) and weights (int32 -> bf16 exact) into d_ws.
// Pass 2: m97-style GEMM: 128x128 tile, BK=32, global_load_lds width-16 staging,
//         4 waves x 4x4 grid of mfma_f32_16x16x32_bf16.
// Workspace needed: (14336*4096 + 4096*4096)*2 = 150,994,944 bytes.

#define AS1 __attribute__((address_space(1)))
#define AS3 __attribute__((address_space(3)))

typedef __attribute__((ext_vector_type(8))) short short8;
typedef __attribute__((ext_vector_type(4))) float f32x4;

static constexpr int IN_F   = 4096;   // K
static constexpr int OUT_F  = 14336;  // N
static constexpr int TOKENS = 2 * 2048; // M

// ---------------- conversion kernels ----------------

__device__ __forceinline__ unsigned short bf16_rne(float f) {
    unsigned int u = __float_as_uint(f);
    u += 0x7fffu + ((u >> 16) & 1u);
    return (unsigned short)(u >> 16);
}

__global__ void convert_x_kernel(const float4* __restrict__ x,
                                 ushort4* __restrict__ xb) {
    size_t i = (size_t)blockIdx.x * blockDim.x + threadIdx.x;
    float4 v = x[i];
    ushort4 r;
    r.x = bf16_rne(v.x); r.y = bf16_rne(v.y);
    r.z = bf16_rne(v.z); r.w = bf16_rne(v.w);
    xb[i] = r;
}

__global__ void convert_w_kernel(const int4* __restrict__ q,
                                 ushort4* __restrict__ wb) {
    size_t i = (size_t)blockIdx.x * blockDim.x + threadIdx.x;
    int4 v = q[i];
    ushort4 r;  // small ints are exact in bf16: truncate fp32 bits
    r.x = (unsigned short)(__float_as_uint((float)(v.x - 8)) >> 16);
    r.y = (unsigned short)(__float_as_uint((float)(v.y - 8)) >> 16);
    r.z = (unsigned short)(__float_as_uint((float)(v.z - 8)) >> 16);
    r.w = (unsigned short)(__float_as_uint((float)(v.w - 8)) >> 16);
    wb[i] = r;
}

// ---------------- GEMM: C[M,N] = A[M,K] * B[N,K]^T, scale/bias epilogue ------

__global__ __launch_bounds__(256)
void gemm_bt_kernel(const unsigned short* __restrict__ A,   // bf16 [M,K]
                    const unsigned short* __restrict__ B,   // bf16 [N,K]
                    const float* __restrict__ scale,        // [N]
                    const float* __restrict__ bias,         // [N]
                    float* __restrict__ C) {                // [M,N]
    constexpr int K  = IN_F;
    constexpr int N  = OUT_F;
    constexpr int BM = 128, BN = 128, BK = 32;

    __shared__ __align__(16) unsigned short sA[BM * BK]; // 8 KiB
    __shared__ __align__(16) unsigned short sB[BN * BK]; // 8 KiB

    const int tid  = threadIdx.x;
    const int wave = tid >> 6;
    const int lane = tid & 63;
    const int l16  = lane & 15;
    const int lq   = lane >> 4;            // quad 0..3

    const int mBase = blockIdx.y * BM;
    const int nBase = blockIdx.x * BN;
    const int wm = (wave >> 1) * 64;       // wave row offset in tile
    const int wn = (wave & 1) * 64;        // wave col offset in tile

    // staging map: thread t stages 16B at lds offset t*16 (wave-uniform base + lane*16)
    const int sr = tid >> 2;               // row within 64-row half
    const int sc = (tid & 3) * 8;          // bf16 col offset (16B chunks)

    const unsigned short* gA = A + (size_t)(mBase + sr) * K + sc;
    const unsigned short* gB = B + (size_t)(nBase + sr) * K + sc;
    unsigned short* lA = &sA[sr * BK + sc];   // == sA + tid*8 shorts
    unsigned short* lB = &sB[sr * BK + sc];

    f32x4 acc[4][4] = {};

    for (int k0 = 0; k0 < K; k0 += BK) {
        __builtin_amdgcn_global_load_lds((const AS1 void*)(gA + k0),
                                         (AS3 void*)lA, 16, 0, 0);
        __builtin_amdgcn_global_load_lds((const AS1 void*)(gA + (size_t)64 * K + k0),
                                         (AS3 void*)(lA + 64 * BK), 16, 0, 0);
        __builtin_amdgcn_global_load_lds((const AS1 void*)(gB + k0),
                                         (AS3 void*)lB, 16, 0, 0);
        __builtin_amdgcn_global_load_lds((const AS1 void*)(gB + (size_t)64 * K + k0),
                                         (AS3 void*)(lB + 64 * BK), 16, 0, 0);
        __syncthreads();

        short8 af[4], bfr[4];
#pragma unroll
        for (int i = 0; i < 4; ++i)
            af[i] = *(const short8*)&sA[(wm + i * 16 + l16) * BK + lq * 8];
#pragma unroll
        for (int j = 0; j < 4; ++j)
            bfr[j] = *(const short8*)&sB[(wn + j * 16 + l16) * BK + lq * 8];

#pragma unroll
        for (int i = 0; i < 4; ++i)
#pragma unroll
            for (int j = 0; j < 4; ++j)
                acc[i][j] = __builtin_amdgcn_mfma_f32_16x16x32_bf16(
                    af[i], bfr[j], acc[i][j], 0, 0, 0);
        __syncthreads();
    }

    // epilogue: C/D layout col = lane&15, row = (lane>>4)*4 + reg
#pragma unroll
    for (int j = 0; j < 4; ++j) {
        const int n = nBase + wn + j * 16 + l16;
        const float s  = scale[n];
        const float bb = bias[n];
#pragma unroll
        for (int i = 0; i < 4; ++i) {
            const int m0 = mBase + wm + i * 16 + lq * 4;
#pragma unroll
            for (int r = 0; r < 4; ++r)
                C[(size_t)(m0 + r) * N + n] = acc[i][j][r] * s + bb;
        }
    }
}

// ---------------- launch ----------------

extern "C" void kernel_launch(void* const* d_in, const int* in_sizes, int n_in,
                              void* d_out, int out_size, void* d_ws, size_t ws_size,
                              hipStream_t stream) {
    const float* x      = (const float*)d_in[0];  // [2,2048,4096] fp32
    const int*   wq     = (const int*)d_in[1];    // [14336,4096] int32 in [0,16)
    const float* wscale = (const float*)d_in[2];  // [14336,1]
    const float* wbias  = (const float*)d_in[3];  // [14336]
    float* out = (float*)d_out;                   // [2,2048,14336] fp32

    unsigned short* wbf = (unsigned short*)d_ws;                    // 117.4 MB
    unsigned short* xbf = wbf + (size_t)OUT_F * IN_F;               // +33.6 MB

    // weight: 58,720,256 elems / 4 per thread / 256 = 57,344 blocks
    convert_w_kernel<<<57344, 256, 0, stream>>>((const int4*)wq, (ushort4*)wbf);
    // x: 16,777,216 elems / 4 per thread / 256 = 16,384 blocks
    convert_x_kernel<<<16384, 256, 0, stream>>>((const float4*)x, (ushort4*)xbf);

    dim3 grid(OUT_F / 128, TOKENS / 128);  // (112, 32)
    gemm_bt_kernel<<<grid, 256, 0, stream>>>(xbf, wbf, wscale, wbias, out);
}